// Round 1
// baseline (660.467 us; speedup 1.0000x reference)
//
#include <hip/hip_runtime.h>

#define T_STEPS 100
#define NTRAJ   8192
#define MBLK    16

typedef __attribute__((ext_vector_type(8))) _Float16 f16x8;
typedef __attribute__((ext_vector_type(4))) float    f32x4;

#define MFMA16(a, b, c) __builtin_amdgcn_mfma_f32_16x16x32_f16((a), (b), (c), 0, 0, 0)

// XOR swizzle on element index within a row (elements are 2B; XOR byte bits 4..6 == elem bits 3..5)
#define SWZ(row, col) ((col) ^ (((row) & 7) << 3))

__device__ __forceinline__ float fast_tanh(float x) {
    x = fminf(15.f, fmaxf(-15.f, x));
    float e = __expf(2.f * x);
    return 1.f - __fdividef(2.f, e + 1.f);
}
__device__ __forceinline__ float fast_sigmoid(float x) {
    x = fminf(30.f, fmaxf(-30.f, x));
    return __fdividef(1.f, 1.f + __expf(-x));
}

// ---------------------------------------------------------------------------
// Weight packing: B-fragment tile order. Tile = 512 f16 = [lane 0..63][j 0..7],
// element (lane, j) = W[k][n] with k = kt*32 + (lane>>4)*8 + j, n = nt*16 + (lane&15).
// Tile map (144 tiles total):
//   [0,14)   ODE L1  Wo1 [64][100]   nt<7,  kt<2   idx = nt*2+kt
//   [14,30)  ODE L2  Wo2 [100][64]   nt<4,  kt<4   idx = 14 + nt*4+kt
//   [30,75)  ZR  L1  Wz1/Wr1 [96][100]  15 nt x 3 kt (z: nt 0..6, pad nt 7, r: nt 8..14)
//   [75,107) ZR  L2  Wz2/Wr2 [100][64]  [gate][nt<4][kt<4]
//   [107,128) H  L1  Wh1 [96][100]   7 nt x 3 kt
//   [128,144) H  L2  Wh2 [100][64]   4 x 4
// ---------------------------------------------------------------------------
__global__ void pack_kernel(const float* __restrict__ Wo1, const float* __restrict__ Wo2,
                            const float* __restrict__ Wz1, const float* __restrict__ Wz2,
                            const float* __restrict__ Wr1, const float* __restrict__ Wr2,
                            const float* __restrict__ Wh1, const float* __restrict__ Wh2,
                            _Float16* __restrict__ P)
{
    int idx = blockIdx.x * 256 + threadIdx.x;
    if (idx >= 144 * 512) return;
    int tile = idx >> 9;
    int r    = idx & 511;
    int lane = r >> 3, j = r & 7;
    int krel = ((lane >> 4) << 3) + j;   // 0..31
    int c16  = lane & 15;
    float val = 0.f;

    if (tile < 14) {                       // ODE L1
        int t = tile, nt = t >> 1, kt = t & 1;
        int k = kt * 32 + krel, n = nt * 16 + c16;
        if (k < 64 && n < 100) val = Wo1[k * 100 + n];
    } else if (tile < 30) {                // ODE L2
        int t = tile - 14, nt = t >> 2, kt = t & 3;
        int k = kt * 32 + krel, n = nt * 16 + c16;
        if (k < 100) val = Wo2[k * 64 + n];
    } else if (tile < 75) {                // ZR L1
        int t = tile - 30, nt = t / 3, kt = t % 3;
        int k = kt * 32 + krel;            // K = 96 exact
        if (nt < 7)      { int n = nt * 16 + c16;        if (n < 100) val = Wz1[k * 100 + n]; }
        else if (nt >= 8){ int n = (nt - 8) * 16 + c16;  if (n < 100) val = Wr1[k * 100 + n]; }
    } else if (tile < 107) {               // ZR L2
        int t = tile - 75, gate = t >> 4, rem = t & 15, nt = rem >> 2, kt = rem & 3;
        int k = kt * 32 + krel, n = nt * 16 + c16;
        const float* W = gate ? Wr2 : Wz2;
        if (k < 100) val = W[k * 64 + n];
    } else if (tile < 128) {               // H L1
        int t = tile - 107, nt = t / 3, kt = t % 3;
        int k = kt * 32 + krel, n = nt * 16 + c16;
        if (n < 100) val = Wh1[k * 100 + n];
    } else {                               // H L2
        int t = tile - 128, nt = t >> 2, kt = t & 3;
        int k = kt * 32 + krel, n = nt * 16 + c16;
        if (k < 100) val = Wh2[k * 64 + n];
    }
    P[idx] = (_Float16)val;
}

__device__ __forceinline__ f16x8 ldsA(const _Float16* buf, int stride, int row, int kcol) {
    return *(const f16x8*)(buf + row * stride + SWZ(row, kcol));
}

// ---------------------------------------------------------------------------
// Main kernel: block = 16 trajectories (one MFMA M-tile), 256 threads = 4 waves
// splitting output columns of each GEMM. 99 sequential steps, 6 barriers/step.
// ---------------------------------------------------------------------------
__global__ __launch_bounds__(256, 2) void odernn_kernel(
    const float* __restrict__ data, const float* __restrict__ ts,
    const float* __restrict__ prior,
    const float* __restrict__ bo1, const float* __restrict__ bo2,
    const float* __restrict__ bz1, const float* __restrict__ bz2,
    const float* __restrict__ br1, const float* __restrict__ br2,
    const float* __restrict__ bh1, const float* __restrict__ bh2,
    const _Float16* __restrict__ P, float* __restrict__ out)
{
    __shared__ __align__(16) _Float16 sYb[MBLK * 64];   // y (f16), GEMM1 input
    __shared__ __align__(16) _Float16 sYX[MBLK * 128];  // [yode | x | 0]
    __shared__ __align__(16) _Float16 sRX[MBLK * 128];  // [rg*yode | x | 0]
    __shared__ __align__(16) _Float16 sH1[MBLK * 128];  // hidden (ODE L1 / H L1)
    __shared__ __align__(16) _Float16 sZR[MBLK * 256];  // [z-hidden(112) pad | r-hidden(112) pad]
    __shared__ float sYF[MBLK * 64];                    // y state, f32
    __shared__ float sYO[MBLK * 64];                    // y_ode, f32
    __shared__ float sZG[MBLK * 64];                    // update gate, f32

    const int tid  = threadIdx.x;
    const int lane = tid & 63;
    const int wv   = tid >> 6;
    const int c16  = lane & 15;
    const int g4   = lane >> 4;
    const int m0   = blockIdx.x * MBLK;
    const f16x8* Pt = (const f16x8*)P;

    // init state from prior; zero LDS pad regions (avoid NaN * 0 in MFMA)
    for (int i = tid; i < MBLK * 64; i += 256) {
        int row = i >> 6, col = i & 63;
        float v = prior[(size_t)(m0 + row) * 64 + col];
        sYF[i] = v;
        sYb[row * 64 + SWZ(row, col)] = (_Float16)v;
    }
    for (int i = tid; i < MBLK * 16; i += 256) {
        int row = i >> 4, col = 112 + (i & 15);
        sH1[row * 128 + SWZ(row, col)] = (_Float16)0.f;
    }
    for (int i = tid; i < MBLK * 32; i += 256) {
        int row = i >> 5, cc = i & 31;
        int col = (cc < 16) ? (112 + cc) : (224 + cc);  // 112..127 and 240..255
        sZR[row * 256 + SWZ(row, col)] = (_Float16)0.f;
        int col2 = 96 + cc;
        sYX[row * 128 + SWZ(row, col2)] = (_Float16)0.f;
        sRX[row * 128 + SWZ(row, col2)] = (_Float16)0.f;
    }
    __syncthreads();

    const float t0 = ts[0], t1 = ts[1];

    for (int s = 0; s < T_STEPS - 1; ++s) {
        const float dt = (s == 0) ? (t1 - t0) : (ts[s - 1] - ts[s]);

        // stage x = data[:, s+1, :] into both concat buffers (cols 64..95)
        for (int i = tid; i < MBLK * 32; i += 256) {
            int row = i >> 5, c = i & 31;
            _Float16 xv = (_Float16)data[((size_t)(m0 + row) * T_STEPS + (s + 1)) * 32 + c];
            int sw = SWZ(row, 64 + c);
            sYX[row * 128 + sw] = xv;
            sRX[row * 128 + sw] = xv;
        }

        // G1: H1 = tanh(y @ Wo1 + bo1)   [16x64]@[64x112]
        {
            f16x8 a0 = ldsA(sYb, 64, c16, (g4 << 3));
            f16x8 a1 = ldsA(sYb, 64, c16, 32 + (g4 << 3));
            int nt0 = (wv < 3) ? 2 * wv : 6;
            int ncnt = (wv < 3) ? 2 : 1;
            for (int q = 0; q < ncnt; ++q) {
                int nt = nt0 + q;
                f32x4 acc = {0.f, 0.f, 0.f, 0.f};
                acc = MFMA16(a0, Pt[(nt * 2 + 0) * 64 + lane], acc);
                acc = MFMA16(a1, Pt[(nt * 2 + 1) * 64 + lane], acc);
                int col = nt * 16 + c16;
                float bias = (col < 100) ? bo1[col] : 0.f;
                #pragma unroll
                for (int r = 0; r < 4; ++r) {
                    int row = g4 * 4 + r;
                    sH1[row * 128 + SWZ(row, col)] = (_Float16)fast_tanh(acc[r] + bias);
                }
            }
        }
        __syncthreads();

        // G2: yode = y + dt*(H1 @ Wo2 + bo2)   [16x128]@[128x64]
        {
            f16x8 a[4];
            #pragma unroll
            for (int kt = 0; kt < 4; ++kt) a[kt] = ldsA(sH1, 128, c16, kt * 32 + (g4 << 3));
            int nt = wv;
            f32x4 acc = {0.f, 0.f, 0.f, 0.f};
            #pragma unroll
            for (int kt = 0; kt < 4; ++kt) acc = MFMA16(a[kt], Pt[(14 + nt * 4 + kt) * 64 + lane], acc);
            int col = nt * 16 + c16;
            float bias = bo2[col];
            #pragma unroll
            for (int r = 0; r < 4; ++r) {
                int row = g4 * 4 + r;
                float yo = sYF[row * 64 + col] + dt * (acc[r] + bias);
                sYO[row * 64 + col] = yo;
                sYX[row * 128 + SWZ(row, col)] = (_Float16)yo;
            }
        }
        __syncthreads();

        // G3: zr-hidden = tanh([yode|x] @ W{z,r}1 + b)   [16x96]@[96x224]
        {
            f16x8 a[3];
            #pragma unroll
            for (int kt = 0; kt < 3; ++kt) a[kt] = ldsA(sYX, 128, c16, kt * 32 + (g4 << 3));
            for (int i = wv; i < 14; i += 4) {
                int bt = (i < 7) ? i : i + 1;  // buffer tile (skip pad tile 7)
                f32x4 acc = {0.f, 0.f, 0.f, 0.f};
                #pragma unroll
                for (int kt = 0; kt < 3; ++kt) acc = MFMA16(a[kt], Pt[(30 + bt * 3 + kt) * 64 + lane], acc);
                int col = bt * 16 + c16;
                int bc = (i < 7) ? col : (col - 128);
                float bias = (bc < 100) ? ((i < 7) ? bz1[bc] : br1[bc]) : 0.f;
                #pragma unroll
                for (int r = 0; r < 4; ++r) {
                    int row = g4 * 4 + r;
                    sZR[row * 256 + SWZ(row, col)] = (_Float16)fast_tanh(acc[r] + bias);
                }
            }
        }
        __syncthreads();

        // G4: zg = sigmoid(zh @ Wz2 + bz2) (waves 0,1) ; rg (waves 2,3), write rg*yode
        {
            int gate = wv >> 1;
            f16x8 a[4];
            #pragma unroll
            for (int kt = 0; kt < 4; ++kt) a[kt] = ldsA(sZR, 256, c16, gate * 128 + kt * 32 + (g4 << 3));
            for (int q = 0; q < 2; ++q) {
                int nt = (wv & 1) * 2 + q;
                f32x4 acc = {0.f, 0.f, 0.f, 0.f};
                #pragma unroll
                for (int kt = 0; kt < 4; ++kt)
                    acc = MFMA16(a[kt], Pt[(75 + gate * 16 + nt * 4 + kt) * 64 + lane], acc);
                int col = nt * 16 + c16;
                if (gate == 0) {
                    float bias = bz2[col];
                    #pragma unroll
                    for (int r = 0; r < 4; ++r) {
                        int row = g4 * 4 + r;
                        sZG[row * 64 + col] = fast_sigmoid(acc[r] + bias);
                    }
                } else {
                    float bias = br2[col];
                    #pragma unroll
                    for (int r = 0; r < 4; ++r) {
                        int row = g4 * 4 + r;
                        float rv = fast_sigmoid(acc[r] + bias) * sYO[row * 64 + col];
                        sRX[row * 128 + SWZ(row, col)] = (_Float16)rv;
                    }
                }
            }
        }
        __syncthreads();

        // G5: H1 = tanh([rg*yode|x] @ Wh1 + bh1)
        {
            f16x8 a[3];
            #pragma unroll
            for (int kt = 0; kt < 3; ++kt) a[kt] = ldsA(sRX, 128, c16, kt * 32 + (g4 << 3));
            int nt0 = (wv < 3) ? 2 * wv : 6;
            int ncnt = (wv < 3) ? 2 : 1;
            for (int q = 0; q < ncnt; ++q) {
                int nt = nt0 + q;
                f32x4 acc = {0.f, 0.f, 0.f, 0.f};
                #pragma unroll
                for (int kt = 0; kt < 3; ++kt) acc = MFMA16(a[kt], Pt[(107 + nt * 3 + kt) * 64 + lane], acc);
                int col = nt * 16 + c16;
                float bias = (col < 100) ? bh1[col] : 0.f;
                #pragma unroll
                for (int r = 0; r < 4; ++r) {
                    int row = g4 * 4 + r;
                    sH1[row * 128 + SWZ(row, col)] = (_Float16)fast_tanh(acc[r] + bias);
                }
            }
        }
        __syncthreads();

        // G6: h = tanh(H1 @ Wh2 + bh2); y = (1-z)*h + z*yode
        {
            f16x8 a[4];
            #pragma unroll
            for (int kt = 0; kt < 4; ++kt) a[kt] = ldsA(sH1, 128, c16, kt * 32 + (g4 << 3));
            int nt = wv;
            f32x4 acc = {0.f, 0.f, 0.f, 0.f};
            #pragma unroll
            for (int kt = 0; kt < 4; ++kt) acc = MFMA16(a[kt], Pt[(128 + nt * 4 + kt) * 64 + lane], acc);
            int col = nt * 16 + c16;
            float bias = bh2[col];
            #pragma unroll
            for (int r = 0; r < 4; ++r) {
                int row = g4 * 4 + r;
                float h = fast_tanh(acc[r] + bias);
                float z = sZG[row * 64 + col];
                float yo = sYO[row * 64 + col];
                float yn = (1.f - z) * h + z * yo;
                sYF[row * 64 + col] = yn;
                sYb[row * 64 + SWZ(row, col)] = (_Float16)yn;
            }
        }
        __syncthreads();
    }

    for (int i = tid; i < MBLK * 64; i += 256) {
        int row = i >> 6, col = i & 63;
        out[(size_t)(m0 + row) * 64 + col] = sYF[i];
    }
}

extern "C" void kernel_launch(void* const* d_in, const int* in_sizes, int n_in,
                              void* d_out, int out_size, void* d_ws, size_t ws_size,
                              hipStream_t stream) {
    const float* data = (const float*)d_in[0];
    const float* ts   = (const float*)d_in[1];
    const float* prior= (const float*)d_in[2];
    const float* Wo1 = (const float*)d_in[3];  const float* bo1 = (const float*)d_in[4];
    const float* Wo2 = (const float*)d_in[5];  const float* bo2 = (const float*)d_in[6];
    const float* Wz1 = (const float*)d_in[7];  const float* bz1 = (const float*)d_in[8];
    const float* Wz2 = (const float*)d_in[9];  const float* bz2 = (const float*)d_in[10];
    const float* Wr1 = (const float*)d_in[11]; const float* br1 = (const float*)d_in[12];
    const float* Wr2 = (const float*)d_in[13]; const float* br2 = (const float*)d_in[14];
    const float* Wh1 = (const float*)d_in[15]; const float* bh1 = (const float*)d_in[16];
    const float* Wh2 = (const float*)d_in[17]; const float* bh2 = (const float*)d_in[18];
    _Float16* P = (_Float16*)d_ws;
    float* out = (float*)d_out;

    hipLaunchKernelGGL(pack_kernel, dim3((144 * 512 + 255) / 256), dim3(256), 0, stream,
                       Wo1, Wo2, Wz1, Wz2, Wr1, Wr2, Wh1, Wh2, P);
    hipLaunchKernelGGL(odernn_kernel, dim3(NTRAJ / MBLK), dim3(256), 0, stream,
                       data, ts, prior, bo1, bo2, bz1, bz2, br1, br2, bh1, bh2, P, out);
}

// Round 2
// 380.488 us; speedup vs baseline: 1.7358x; 1.7358x over previous
//
#include <hip/hip_runtime.h>

#define T_STEPS 100
#define NTRAJ   8192
#define MBLK    16

typedef __attribute__((ext_vector_type(8))) _Float16 f16x8;
typedef __attribute__((ext_vector_type(4))) float    f32x4;

#define MFMA16(a, b, c) __builtin_amdgcn_mfma_f32_16x16x32_f16((a), (b), (c), 0, 0, 0)

// XOR swizzle on element index within a row (2B elems; XOR elem bits 3..5)
#define SWZ(row, col) ((col) ^ (((row) & 7) << 3))

// exp-based, saturation-safe without clamps: e=inf -> rcp(inf)=0 -> 1; e=0 -> -1/0 paths ok
__device__ __forceinline__ float fast_tanh(float x) {
    float e = __expf(2.f * x);
    return 1.f - 2.f * __builtin_amdgcn_rcpf(1.f + e);
}
__device__ __forceinline__ float fast_sigmoid(float x) {
    float e = __expf(-x);
    return __builtin_amdgcn_rcpf(1.f + e);
}

// ---------------------------------------------------------------------------
// Weight packing (unchanged from round 0): B-fragment tile order, 144 tiles.
// ---------------------------------------------------------------------------
__global__ void pack_kernel(const float* __restrict__ Wo1, const float* __restrict__ Wo2,
                            const float* __restrict__ Wz1, const float* __restrict__ Wz2,
                            const float* __restrict__ Wr1, const float* __restrict__ Wr2,
                            const float* __restrict__ Wh1, const float* __restrict__ Wh2,
                            _Float16* __restrict__ P)
{
    int idx = blockIdx.x * 256 + threadIdx.x;
    if (idx >= 144 * 512) return;
    int tile = idx >> 9;
    int r    = idx & 511;
    int lane = r >> 3, j = r & 7;
    int krel = ((lane >> 4) << 3) + j;   // 0..31
    int c16  = lane & 15;
    float val = 0.f;

    if (tile < 14) {                       // ODE L1
        int t = tile, nt = t >> 1, kt = t & 1;
        int k = kt * 32 + krel, n = nt * 16 + c16;
        if (k < 64 && n < 100) val = Wo1[k * 100 + n];
    } else if (tile < 30) {                // ODE L2
        int t = tile - 14, nt = t >> 2, kt = t & 3;
        int k = kt * 32 + krel, n = nt * 16 + c16;
        if (k < 100) val = Wo2[k * 64 + n];
    } else if (tile < 75) {                // ZR L1
        int t = tile - 30, nt = t / 3, kt = t % 3;
        int k = kt * 32 + krel;            // K = 96 exact
        if (nt < 7)      { int n = nt * 16 + c16;        if (n < 100) val = Wz1[k * 100 + n]; }
        else if (nt >= 8){ int n = (nt - 8) * 16 + c16;  if (n < 100) val = Wr1[k * 100 + n]; }
    } else if (tile < 107) {               // ZR L2
        int t = tile - 75, gate = t >> 4, rem = t & 15, nt = rem >> 2, kt = rem & 3;
        int k = kt * 32 + krel, n = nt * 16 + c16;
        const float* W = gate ? Wr2 : Wz2;
        if (k < 100) val = W[k * 64 + n];
    } else if (tile < 128) {               // H L1
        int t = tile - 107, nt = t / 3, kt = t % 3;
        int k = kt * 32 + krel, n = nt * 16 + c16;
        if (n < 100) val = Wh1[k * 100 + n];
    } else {                               // H L2
        int t = tile - 128, nt = t >> 2, kt = t & 3;
        int k = kt * 32 + krel, n = nt * 16 + c16;
        if (k < 100) val = Wh2[k * 64 + n];
    }
    P[idx] = (_Float16)val;
}

__device__ __forceinline__ f16x8 ldsA(const _Float16* buf, int stride, int row, int kcol) {
    return *(const f16x8*)(buf + row * stride + SWZ(row, kcol));
}

// ---------------------------------------------------------------------------
// Main kernel. Block = 16 trajectories, 4 waves split N-tiles.
// State y, y_ode, z-gate live in registers (producer lane == consumer lane by
// assigning G2/G4/G6 column tile nt=wv to wave wv). Biases preloaded to regs.
// ---------------------------------------------------------------------------
__global__ __launch_bounds__(256, 2) void odernn_kernel(
    const float* __restrict__ data, const float* __restrict__ ts,
    const float* __restrict__ prior,
    const float* __restrict__ bo1, const float* __restrict__ bo2,
    const float* __restrict__ bz1, const float* __restrict__ bz2,
    const float* __restrict__ br1, const float* __restrict__ br2,
    const float* __restrict__ bh1, const float* __restrict__ bh2,
    const _Float16* __restrict__ P, float* __restrict__ out)
{
    __shared__ __align__(16) _Float16 sYb[MBLK * 64];   // y (f16), G1 A input
    __shared__ __align__(16) _Float16 sYX[MBLK * 128];  // [yode | x | 0]
    __shared__ __align__(16) _Float16 sRX[MBLK * 128];  // [rg*yode | x | 0]
    __shared__ __align__(16) _Float16 sH1[MBLK * 128];  // hidden (ODE L1 / H L1)
    __shared__ __align__(16) _Float16 sZR[MBLK * 256];  // [z-hidden(112)+pad | r-hidden(112)+pad]

    const int tid  = threadIdx.x;
    const int lane = tid & 63;
    const int wv   = tid >> 6;
    const int c16  = lane & 15;
    const int g4   = lane >> 4;
    const int m0   = blockIdx.x * MBLK;
    const int colw = wv * 16 + c16;              // this lane's "own" column
    const f16x8* Pt = (const f16x8*)P;

    // ---- preload biases into registers (step-invariant per lane) ----
    float b_o1[2], b_h1[2], b_zr[4];
    {
        int c0 = wv * 16 + c16, c1 = (wv + 4) * 16 + c16;
        b_o1[0] = (c0 < 100) ? bo1[c0] : 0.f;
        b_h1[0] = (c0 < 100) ? bh1[c0] : 0.f;
        b_o1[1] = (wv + 4 < 7 && c1 < 100) ? bo1[c1] : 0.f;
        b_h1[1] = (wv + 4 < 7 && c1 < 100) ? bh1[c1] : 0.f;
        #pragma unroll
        for (int q = 0; q < 4; ++q) {
            int i = wv + 4 * q;
            float v = 0.f;
            if (i < 14) {
                int bt = (i < 7) ? i : i + 1;
                int col = bt * 16 + c16;
                int bc = (i < 7) ? col : col - 128;
                if (bc < 100) v = (i < 7) ? bz1[bc] : br1[bc];
            }
            b_zr[q] = v;
        }
    }
    const float b_o2 = bo2[colw], b_z2 = bz2[colw], b_r2 = br2[colw], b_h2 = bh2[colw];

    // ---- preload B-fragments for the small latency-bound phases G2/G6 ----
    f16x8 Bo2[4], Bh2[4];
    #pragma unroll
    for (int kt = 0; kt < 4; ++kt) {
        Bo2[kt] = Pt[(14 + wv * 4 + kt) * 64 + lane];
        Bh2[kt] = Pt[(128 + wv * 4 + kt) * 64 + lane];
    }

    // ---- init: y state in regs, sYb, zero LDS pads ----
    float y[4];
    #pragma unroll
    for (int r = 0; r < 4; ++r) {
        int row = g4 * 4 + r;
        y[r] = prior[(size_t)(m0 + row) * 64 + colw];
        sYb[row * 64 + SWZ(row, colw)] = (_Float16)y[r];
    }
    for (int i = tid; i < MBLK * 16; i += 256) {
        int row = i >> 4, col = 112 + (i & 15);
        sH1[row * 128 + SWZ(row, col)] = (_Float16)0.f;
    }
    for (int i = tid; i < MBLK * 32; i += 256) {
        int row = i >> 5, cc = i & 31;
        int col = (cc < 16) ? (112 + cc) : (224 + cc);
        sZR[row * 256 + SWZ(row, col)] = (_Float16)0.f;
        int col2 = 96 + cc;
        sYX[row * 128 + SWZ(row, col2)] = (_Float16)0.f;
        sRX[row * 128 + SWZ(row, col2)] = (_Float16)0.f;
    }
    __syncthreads();

    const float t0 = ts[0], t1 = ts[1];

    #pragma unroll 1
    for (int s = 0; s < T_STEPS - 1; ++s) {
        const float dt = (s == 0) ? (t1 - t0) : (ts[s - 1] - ts[s]);

        // ---- x prefetch into regs (consumed after G1's compute) ----
        const int xrow0 = tid >> 5, xc0 = tid & 31;
        const int xrow1 = (tid + 256) >> 5, xc1 = tid & 31;
        float xr0 = data[((size_t)(m0 + xrow0) * T_STEPS + (s + 1)) * 32 + xc0];
        float xr1 = data[((size_t)(m0 + xrow1) * T_STEPS + (s + 1)) * 32 + xc1];

        // ---- G1: H1 = tanh(y @ Wo1 + bo1)  [16x64]@[64x112] ----
        {
            f16x8 a0 = ldsA(sYb, 64, c16, (g4 << 3));
            f16x8 a1 = ldsA(sYb, 64, c16, 32 + (g4 << 3));
            #pragma unroll
            for (int t = 0; t < 2; ++t) {
                int nt = wv + 4 * t;
                if (nt < 7) {
                    f32x4 acc = {0.f, 0.f, 0.f, 0.f};
                    acc = MFMA16(a0, Pt[(nt * 2 + 0) * 64 + lane], acc);
                    acc = MFMA16(a1, Pt[(nt * 2 + 1) * 64 + lane], acc);
                    int col = nt * 16 + c16;
                    #pragma unroll
                    for (int r = 0; r < 4; ++r) {
                        int row = g4 * 4 + r;
                        sH1[row * 128 + SWZ(row, col)] = (_Float16)fast_tanh(acc[r] + b_o1[t]);
                    }
                }
            }
        }
        // ---- stage x into both concat buffers (cols 64..95) ----
        {
            _Float16 xv0 = (_Float16)xr0, xv1 = (_Float16)xr1;
            int sw0 = xrow0 * 128 + SWZ(xrow0, 64 + xc0);
            int sw1 = xrow1 * 128 + SWZ(xrow1, 64 + xc1);
            sYX[sw0] = xv0; sRX[sw0] = xv0;
            sYX[sw1] = xv1; sRX[sw1] = xv1;
        }
        __syncthreads();

        // ---- G2: yode = y + dt*(H1 @ Wo2 + bo2); yode kept in regs ----
        float yo[4];
        {
            f32x4 acc = {0.f, 0.f, 0.f, 0.f};
            #pragma unroll
            for (int kt = 0; kt < 4; ++kt) {
                f16x8 a = ldsA(sH1, 128, c16, kt * 32 + (g4 << 3));
                acc = MFMA16(a, Bo2[kt], acc);
            }
            #pragma unroll
            for (int r = 0; r < 4; ++r) {
                int row = g4 * 4 + r;
                yo[r] = y[r] + dt * (acc[r] + b_o2);
                sYX[row * 128 + SWZ(row, colw)] = (_Float16)yo[r];
            }
        }
        __syncthreads();

        // ---- G3: zr-hidden = tanh([yode|x] @ W{z,r}1 + b)  [16x96]@[96x224] ----
        {
            f16x8 a[3];
            #pragma unroll
            for (int kt = 0; kt < 3; ++kt) a[kt] = ldsA(sYX, 128, c16, kt * 32 + (g4 << 3));
            #pragma unroll
            for (int q = 0; q < 4; ++q) {
                int i = wv + 4 * q;
                if (i < 14) {
                    int bt = (i < 7) ? i : i + 1;
                    f32x4 acc = {0.f, 0.f, 0.f, 0.f};
                    #pragma unroll
                    for (int kt = 0; kt < 3; ++kt)
                        acc = MFMA16(a[kt], Pt[(30 + bt * 3 + kt) * 64 + lane], acc);
                    int col = bt * 16 + c16;
                    #pragma unroll
                    for (int r = 0; r < 4; ++r) {
                        int row = g4 * 4 + r;
                        sZR[row * 256 + SWZ(row, col)] = (_Float16)fast_tanh(acc[r] + b_zr[q]);
                    }
                }
            }
        }
        __syncthreads();

        // ---- G4: wave wv owns column tile nt=wv for BOTH gates.
        //      zg -> regs (consumed by G6 same lane); rg*yode -> sRX ----
        float zg[4];
        {
            f32x4 accz = {0.f, 0.f, 0.f, 0.f}, accr = {0.f, 0.f, 0.f, 0.f};
            #pragma unroll
            for (int kt = 0; kt < 4; ++kt) {
                f16x8 az = ldsA(sZR, 256, c16, kt * 32 + (g4 << 3));
                f16x8 ar = ldsA(sZR, 256, c16, 128 + kt * 32 + (g4 << 3));
                accz = MFMA16(az, Pt[(75 + wv * 4 + kt) * 64 + lane], accz);
                accr = MFMA16(ar, Pt[(91 + wv * 4 + kt) * 64 + lane], accr);
            }
            #pragma unroll
            for (int r = 0; r < 4; ++r) {
                int row = g4 * 4 + r;
                zg[r] = fast_sigmoid(accz[r] + b_z2);
                float rv = fast_sigmoid(accr[r] + b_r2) * yo[r];
                sRX[row * 128 + SWZ(row, colw)] = (_Float16)rv;
            }
        }
        __syncthreads();

        // ---- G5: H1 = tanh([rg*yode|x] @ Wh1 + bh1) ----
        {
            f16x8 a[3];
            #pragma unroll
            for (int kt = 0; kt < 3; ++kt) a[kt] = ldsA(sRX, 128, c16, kt * 32 + (g4 << 3));
            #pragma unroll
            for (int t = 0; t < 2; ++t) {
                int nt = wv + 4 * t;
                if (nt < 7) {
                    f32x4 acc = {0.f, 0.f, 0.f, 0.f};
                    #pragma unroll
                    for (int kt = 0; kt < 3; ++kt)
                        acc = MFMA16(a[kt], Pt[(107 + nt * 3 + kt) * 64 + lane], acc);
                    int col = nt * 16 + c16;
                    #pragma unroll
                    for (int r = 0; r < 4; ++r) {
                        int row = g4 * 4 + r;
                        sH1[row * 128 + SWZ(row, col)] = (_Float16)fast_tanh(acc[r] + b_h1[t]);
                    }
                }
            }
        }
        __syncthreads();

        // ---- G6: h = tanh(H1 @ Wh2 + bh2); y = (1-z)*h + z*yode (all regs) ----
        {
            f32x4 acc = {0.f, 0.f, 0.f, 0.f};
            #pragma unroll
            for (int kt = 0; kt < 4; ++kt) {
                f16x8 a = ldsA(sH1, 128, c16, kt * 32 + (g4 << 3));
                acc = MFMA16(a, Bh2[kt], acc);
            }
            #pragma unroll
            for (int r = 0; r < 4; ++r) {
                int row = g4 * 4 + r;
                float h = fast_tanh(acc[r] + b_h2);
                y[r] = (1.f - zg[r]) * h + zg[r] * yo[r];
                sYb[row * 64 + SWZ(row, colw)] = (_Float16)y[r];
            }
        }
        __syncthreads();
    }

    #pragma unroll
    for (int r = 0; r < 4; ++r) {
        int row = g4 * 4 + r;
        out[(size_t)(m0 + row) * 64 + colw] = y[r];
    }
}

extern "C" void kernel_launch(void* const* d_in, const int* in_sizes, int n_in,
                              void* d_out, int out_size, void* d_ws, size_t ws_size,
                              hipStream_t stream) {
    const float* data = (const float*)d_in[0];
    const float* ts   = (const float*)d_in[1];
    const float* prior= (const float*)d_in[2];
    const float* Wo1 = (const float*)d_in[3];  const float* bo1 = (const float*)d_in[4];
    const float* Wo2 = (const float*)d_in[5];  const float* bo2 = (const float*)d_in[6];
    const float* Wz1 = (const float*)d_in[7];  const float* bz1 = (const float*)d_in[8];
    const float* Wz2 = (const float*)d_in[9];  const float* bz2 = (const float*)d_in[10];
    const float* Wr1 = (const float*)d_in[11]; const float* br1 = (const float*)d_in[12];
    const float* Wr2 = (const float*)d_in[13]; const float* br2 = (const float*)d_in[14];
    const float* Wh1 = (const float*)d_in[15]; const float* bh1 = (const float*)d_in[16];
    const float* Wh2 = (const float*)d_in[17]; const float* bh2 = (const float*)d_in[18];
    _Float16* P = (_Float16*)d_ws;
    float* out = (float*)d_out;

    hipLaunchKernelGGL(pack_kernel, dim3((144 * 512 + 255) / 256), dim3(256), 0, stream,
                       Wo1, Wo2, Wz1, Wz2, Wr1, Wr2, Wh1, Wh2, P);
    hipLaunchKernelGGL(odernn_kernel, dim3(NTRAJ / MBLK), dim3(256), 0, stream,
                       data, ts, prior, bo1, bo2, bz1, bz2, br1, br2, bh1, bh2, P, out);
}